// Round 7
// baseline (252.095 us; speedup 1.0000x reference)
//
#include <hip/hip_runtime.h>

#define LN_EPS 1e-5f

typedef short bf16x8 __attribute__((ext_vector_type(8)));
typedef float f32x4  __attribute__((ext_vector_type(4)));

__device__ __forceinline__ unsigned short f2bf(float f) {
  unsigned u = __float_as_uint(f);
  u += 0x7fffu + ((u >> 16) & 1u);          // RNE
  return (unsigned short)(u >> 16);
}
__device__ __forceinline__ float bf2f(unsigned short s) {
  return __uint_as_float(((unsigned)s) << 16);
}

__device__ __forceinline__ bf16x8 pack8(float4 a, float4 b) {
  bf16x8 v;
  v[0] = (short)f2bf(a.x); v[1] = (short)f2bf(a.y);
  v[2] = (short)f2bf(a.z); v[3] = (short)f2bf(a.w);
  v[4] = (short)f2bf(b.x); v[5] = (short)f2bf(b.y);
  v[6] = (short)f2bf(b.z); v[7] = (short)f2bf(b.w);
  return v;
}

// ---------------------------------------------------------------------------
// Prep (byte-identical to the verified r0 kernel): BT = pre-tiled bf16 image
// of [W_in: chunks 0..7 | CB: chunks 8..23], c2, code_out = CB@W_out^T,
// loss/ticket zero.
// ---------------------------------------------------------------------------
__global__ __launch_bounds__(256) void prep_kernel(
    const float* __restrict__ codebook, const float* __restrict__ W_in,
    const float* __restrict__ W_out,
    float* __restrict__ loss_acc, unsigned* __restrict__ ticket,
    float* __restrict__ c2, float* __restrict__ code_out,
    unsigned short* __restrict__ BT) {
  const int b = blockIdx.x, t = threadIdx.x;
  if (b < 32) {
    if (b == 0 && t == 0) { *loss_acc = 0.f; *ticket = 0u; }
    int e = b * 8 + (t >> 5);
    int c32 = t & 31, ks = c32 >> 2, kq = c32 & 3;
    const float* src = W_in + e * 256 + c32 * 8;
    float4 x0 = *(const float4*)src, x1 = *(const float4*)(src + 4);
    *(bf16x8*)(BT + ks * 8192 + (e >> 6) * 2048 + ((e >> 4) & 3) * 512 +
               kq * 128 + (e & 15) * 8) = pack8(x0, x1);
  } else if (b < 96) {
    int code = (b - 32) * 8 + (t >> 5);
    int c32 = t & 31, ks = c32 >> 2, kq = c32 & 3;
    const float* src = codebook + code * 256 + c32 * 8;
    float4 x0 = *(const float4*)src, x1 = *(const float4*)(src + 4);
    int cl = code & 255;
    int chunk = 8 + (code >> 8) * 8 + ks;
    *(bf16x8*)(BT + chunk * 8192 + (cl >> 6) * 2048 + ((cl >> 4) & 3) * 512 +
               kq * 128 + (cl & 15) * 8) = pack8(x0, x1);
    float s = x0.x * x0.x + x0.y * x0.y + x0.z * x0.z + x0.w * x0.w +
              x1.x * x1.x + x1.y * x1.y + x1.z * x1.z + x1.w * x1.w;
    s += __shfl_xor(s, 1);  s += __shfl_xor(s, 2);
    s += __shfl_xor(s, 4);  s += __shfl_xor(s, 8);
    s += __shfl_xor(s, 16);
    if ((t & 31) == 0) c2[code] = s;
  } else {
    __shared__ float Cs[32][260];
    __shared__ float Ws[16][260];
    int bi = b - 96, ci = bi & 15, ei = bi >> 4;
    {
      int row = t >> 4, col = (t & 15) * 16;
      const float4* s = (const float4*)(W_out + (size_t)(ei * 16 + row) * 256 + col);
      float4* d = (float4*)&Ws[row][col];
      d[0] = s[0]; d[1] = s[1]; d[2] = s[2]; d[3] = s[3];
    }
    {
      int row = t >> 3, col = (t & 7) * 32;
      const float4* s = (const float4*)(codebook + (size_t)(ci * 32 + row) * 256 + col);
      float4* d = (float4*)&Cs[row][col];
      #pragma unroll
      for (int k = 0; k < 8; k++) d[k] = s[k];
    }
    __syncthreads();
    int c = t & 31, e0 = t >> 5;
    float a0 = 0.f, a1 = 0.f;
    #pragma unroll 4
    for (int d = 0; d < 256; d += 4) {
      float4 cv = *(const float4*)&Cs[c][d];
      float4 w0 = *(const float4*)&Ws[e0][d];
      float4 w1 = *(const float4*)&Ws[e0 + 8][d];
      a0 += cv.x * w0.x + cv.y * w0.y + cv.z * w0.z + cv.w * w0.w;
      a1 += cv.x * w1.x + cv.y * w1.y + cv.z * w1.z + cv.w * w1.w;
    }
    code_out[(size_t)(ci * 32 + c) * 256 + ei * 16 + e0]     = a0;
    code_out[(size_t)(ci * 32 + c) * 256 + ei * 16 + e0 + 8] = a1;
  }
}

// ---------------------------------------------------------------------------
// Main: byte-identical to the verified r0 kernel EXCEPT phase 3, which is
// re-partitioned to 8-lanes-per-row (one pass per row set, 6 shuffles/wave
// instead of 96).  Single-variable change; everything upstream unchanged.
// ---------------------------------------------------------------------------
__global__ __launch_bounds__(512, 4) void main_kernel(
    const float* __restrict__ hidden, const int* __restrict__ mask,
    const float* __restrict__ gamma, const float* __restrict__ beta,
    const float* __restrict__ c2g, const float* __restrict__ code_out,
    const unsigned short* __restrict__ BT,
    float* __restrict__ loss_acc, unsigned* __restrict__ ticket,
    float* __restrict__ out) {

  __shared__ unsigned short HZ[64 * 264];   // H then Z (33792 B), stride 264
  __shared__ float    z2[64];
  __shared__ unsigned sminp[512];
  __shared__ int      ridx[64];

  const int t    = threadIdx.x;             // 0..511
  const int lane = t & 63;
  const int w    = t >> 6;                  // wave 0..7
  const int l15  = lane & 15;
  const int quad = lane >> 4;
  const int row0 = blockIdx.x * 64;

  // c2 for this wave's 2x32 code columns
  float ccp[2][2];
  #pragma unroll
  for (int p = 0; p < 2; p++)
    #pragma unroll
    for (int j = 0; j < 2; j++)
      ccp[p][j] = c2g[p * 256 + w * 32 + j * 16 + l15];

  // ---- stage H: contiguous global reads, b128 LDS writes ----
  {
    #pragma unroll
    for (int i = 0; i < 4; i++) {
      int flat = (t * 8) + i * 4096;        // float index in 64x256 tile
      int r = flat >> 8, c = flat & 255;
      const float* src = hidden + (size_t)row0 * 256 + flat;
      float4 x0 = *(const float4*)src, x1 = *(const float4*)(src + 4);
      *(bf16x8*)(HZ + r * 264 + c) = pack8(x0, x1);
    }
  }
  __syncthreads();   // H visible

  const f32x4 zf = {0.f, 0.f, 0.f, 0.f};
  f32x4 acc[4][2];
  #pragma unroll
  for (int i = 0; i < 4; i++)
    #pragma unroll
    for (int j = 0; j < 2; j++) acc[i][j] = zf;

  // b-frag address: BT + chunk*8192 + w*1024 + j*512 + quad*128 + l15*8
  const unsigned short* BTw = BT + w * 1024 + lane * 8;

  // ---------------- Phase 1: Z = H * W_in^T ----------------
  #pragma unroll 2
  for (int ks = 0; ks < 8; ks++) {
    const unsigned short* bp = BTw + ks * 8192;
    bf16x8 b0 = *(const bf16x8*)(bp);
    bf16x8 b1 = *(const bf16x8*)(bp + 512);
    bf16x8 a[4];
    #pragma unroll
    for (int i = 0; i < 4; i++)
      a[i] = *(const bf16x8*)(HZ + (i * 16 + l15) * 264 + ks * 32 + quad * 8);
    #pragma unroll
    for (int i = 0; i < 4; i++) {
      acc[i][0] = __builtin_amdgcn_mfma_f32_16x16x32_bf16(a[i], b0, acc[i][0], 0, 0, 0);
      acc[i][1] = __builtin_amdgcn_mfma_f32_16x16x32_bf16(a[i], b1, acc[i][1], 0, 0, 0);
    }
  }

  __syncthreads();   // all H reads done
  // Z epilogue: C/D layout row = quad*4+reg, col = lane&15
  #pragma unroll
  for (int i = 0; i < 4; i++)
    #pragma unroll
    for (int j = 0; j < 2; j++)
      #pragma unroll
      for (int r = 0; r < 4; r++)
        HZ[(i * 16 + quad * 4 + r) * 264 + (w * 32 + j * 16 + l15)] =
            f2bf(acc[i][j][r]);
  __syncthreads();   // Z visible

  { // |z|^2 per row from bf16 Z (consistent with scores)
    int zr = t >> 3, part = t & 7;
    float s = 0.f;
    const unsigned short* zp = HZ + zr * 264 + part * 32;
    #pragma unroll
    for (int c = 0; c < 32; c += 8) {
      bf16x8 v = *(const bf16x8*)(zp + c);
      #pragma unroll
      for (int e = 0; e < 8; e++) { float f = bf2f((unsigned short)v[e]); s += f * f; }
    }
    s += __shfl_xor(s, 1);
    s += __shfl_xor(s, 2);
    s += __shfl_xor(s, 4);
    if (part == 0) z2[zr] = s;
  }

  // ---------------- Phase 2: scores + packed argmin ----------------
  unsigned runp[16];
  #pragma unroll
  for (int r = 0; r < 16; r++) runp[r] = 0xFFFFFFFFu;

  #pragma unroll
  for (int pass = 0; pass < 2; pass++) {
    #pragma unroll
    for (int i = 0; i < 4; i++)
      #pragma unroll
      for (int j = 0; j < 2; j++) acc[i][j] = zf;

    #pragma unroll 2
    for (int ks = 0; ks < 8; ks++) {
      const unsigned short* bp = BTw + (8 + pass * 8 + ks) * 8192;
      bf16x8 b0 = *(const bf16x8*)(bp);
      bf16x8 b1 = *(const bf16x8*)(bp + 512);
      bf16x8 a[4];
      #pragma unroll
      for (int i = 0; i < 4; i++)
        a[i] = *(const bf16x8*)(HZ + (i * 16 + l15) * 264 + ks * 32 + quad * 8);
      #pragma unroll
      for (int i = 0; i < 4; i++) {
        acc[i][0] = __builtin_amdgcn_mfma_f32_16x16x32_bf16(a[i], b0, acc[i][0], 0, 0, 0);
        acc[i][1] = __builtin_amdgcn_mfma_f32_16x16x32_bf16(a[i], b1, acc[i][1], 0, 0, 0);
      }
    }
    // fold: m = c2 - 2 z.c ; pack sortable (dist | 9-bit code); min
    #pragma unroll
    for (int i = 0; i < 4; i++)
      #pragma unroll
      for (int j = 0; j < 2; j++) {
        int code = pass * 256 + w * 32 + j * 16 + l15;
        float cc = ccp[pass][j];
        #pragma unroll
        for (int r = 0; r < 4; r++) {
          float m = cc - 2.f * acc[i][j][r];
          unsigned bits = __float_as_uint(m);
          unsigned u = bits ^ (0x80000000u | (unsigned)((int)bits >> 31));
          unsigned p = (u & 0xFFFFFE00u) | (unsigned)code;
          int ri = i * 4 + r;
          runp[ri] = min(runp[ri], p);
        }
      }
  }

  // reduce across the 16 lanes of each quad group
  #pragma unroll
  for (int ri = 0; ri < 16; ri++) {
    unsigned v = runp[ri];
    v = min(v, (unsigned)__shfl_xor((int)v, 1));
    v = min(v, (unsigned)__shfl_xor((int)v, 2));
    v = min(v, (unsigned)__shfl_xor((int)v, 4));
    v = min(v, (unsigned)__shfl_xor((int)v, 8));
    if (l15 == 0) {
      int i = ri >> 2, r = ri & 3;
      sminp[w * 64 + (i * 16 + quad * 4 + r)] = v;
    }
  }
  __syncthreads();

  if (t < 64) { // merge 8 waves, finalize idx + dist, block loss + ticket
    int row = t;
    unsigned bv = sminp[row];
    #pragma unroll
    for (int ww = 1; ww < 8; ww++) bv = min(bv, sminp[ww * 64 + row]);
    ridx[row] = (int)(bv & 511u);
    unsigned u = bv & 0xFFFFFE00u;
    unsigned bits = (u & 0x80000000u) ? (u ^ 0x80000000u) : ~u;
    float dist = z2[row] + __uint_as_float(bits);
    #pragma unroll
    for (int m = 1; m < 64; m <<= 1) dist += __shfl_xor(dist, m);
    if (t == 0) {
      atomicAdd(loss_acc, dist);
      __threadfence();
      unsigned done = atomicAdd(ticket, 1u);
      if (done == gridDim.x - 1) {
        float total = atomicAdd(loss_acc, 0.f);
        out[16777216] = 1.25f * total * (1.f / 16777216.f);
      }
    }
  }
  __syncthreads();

  // ---- phase 3 (THE single change): 8-lanes-per-row LayerNorm ----
  // row = w*8 + (lane>>3); lane part = lane&7 covers cols part*32..part*32+31.
  // 6 shuffles per wave (was 96); hidden/code_out re-reads are cache-hot
  // (FETCH counter shows hidden fetched once).
  {
    const int row  = w * 8 + (lane >> 3);
    const int part = lane & 7;
    const int gr   = row0 + row;
    const float mf = mask[gr] ? 1.f : 0.f;
    const int code = ridx[row];
    const float* hsrc = hidden   + (size_t)gr   * 256 + part * 32;
    const float* osrc = code_out + (size_t)code * 256 + part * 32;
    float s = 0.f, sq = 0.f;
    #pragma unroll
    for (int k = 0; k < 8; k++) {
      float4 h4 = *(const float4*)(hsrc + k * 4);
      float4 o4 = *(const float4*)(osrc + k * 4);
      float a0 = h4.x + mf * o4.x, a1 = h4.y + mf * o4.y;
      float a2 = h4.z + mf * o4.z, a3 = h4.w + mf * o4.w;
      s  += (a0 + a1) + (a2 + a3);
      sq += (a0 * a0 + a1 * a1) + (a2 * a2 + a3 * a3);
    }
    s += __shfl_xor(s, 1);  sq += __shfl_xor(sq, 1);
    s += __shfl_xor(s, 2);  sq += __shfl_xor(sq, 2);
    s += __shfl_xor(s, 4);  sq += __shfl_xor(sq, 4);
    float mean = s * (1.f / 256.f);
    float var  = sq * (1.f / 256.f) - mean * mean;
    float rstd = rsqrtf(var + LN_EPS);
    float* dst = out + (size_t)gr * 256 + part * 32;
    const float* gsrc = gamma + part * 32;
    const float* bsrc = beta  + part * 32;
    #pragma unroll
    for (int k = 0; k < 8; k++) {
      float4 h4 = *(const float4*)(hsrc + k * 4);
      float4 o4 = *(const float4*)(osrc + k * 4);
      float4 g4 = *(const float4*)(gsrc + k * 4);
      float4 b4 = *(const float4*)(bsrc + k * 4);
      float4 res;
      res.x = (h4.x + mf * o4.x - mean) * rstd * g4.x + b4.x;
      res.y = (h4.y + mf * o4.y - mean) * rstd * g4.y + b4.y;
      res.z = (h4.z + mf * o4.z - mean) * rstd * g4.z + b4.z;
      res.w = (h4.w + mf * o4.w - mean) * rstd * g4.w + b4.w;
      *(float4*)(dst + k * 4) = res;
    }
  }
}

extern "C" void kernel_launch(void* const* d_in, const int* in_sizes, int n_in,
                              void* d_out, int out_size, void* d_ws, size_t ws_size,
                              hipStream_t stream) {
  (void)in_sizes; (void)n_in; (void)out_size; (void)ws_size;
  const float* hidden   = (const float*)d_in[0];
  const int*   mask     = (const int*)d_in[1];
  const float* codebook = (const float*)d_in[2];
  const float* W_in     = (const float*)d_in[3];
  const float* W_out    = (const float*)d_in[4];
  const float* gamma    = (const float*)d_in[5];
  const float* beta     = (const float*)d_in[6];
  float* out = (float*)d_out;

  float* wsf      = (float*)d_ws;
  float* loss_acc = wsf;                        // [1]
  unsigned* ticket = (unsigned*)(wsf + 1);      // [1]
  float* c2       = wsf + 64;                   // [512]
  float* code_out = wsf + 64 + 512;             // [512*256]
  unsigned short* BT = (unsigned short*)(wsf + 64 + 512 + 512 * 256); // 24*8192 bf16

  prep_kernel<<<352, 256, 0, stream>>>(codebook, W_in, W_out, loss_acc, ticket,
                                       c2, code_out, BT);
  main_kernel<<<1024, 512, 0, stream>>>(hidden, mask, gamma, beta, c2, code_out,
                                        BT, loss_acc, ticket, out);
}

// Round 8
// 196.067 us; speedup vs baseline: 1.2858x; 1.2858x over previous
//
#include <hip/hip_runtime.h>

#define LN_EPS 1e-5f

typedef short bf16x8 __attribute__((ext_vector_type(8)));
typedef float f32x4  __attribute__((ext_vector_type(4)));

__device__ __forceinline__ unsigned short f2bf(float f) {
  unsigned u = __float_as_uint(f);
  u += 0x7fffu + ((u >> 16) & 1u);          // RNE
  return (unsigned short)(u >> 16);
}
__device__ __forceinline__ float bf2f(unsigned short s) {
  return __uint_as_float(((unsigned)s) << 16);
}

__device__ __forceinline__ bf16x8 pack8(float4 a, float4 b) {
  bf16x8 v;
  v[0] = (short)f2bf(a.x); v[1] = (short)f2bf(a.y);
  v[2] = (short)f2bf(a.z); v[3] = (short)f2bf(a.w);
  v[4] = (short)f2bf(b.x); v[5] = (short)f2bf(b.y);
  v[6] = (short)f2bf(b.z); v[7] = (short)f2bf(b.w);
  return v;
}

// ---------------------------------------------------------------------------
// Prep (byte-identical to the verified r0 kernel): BT = pre-tiled bf16 image
// of [W_in: chunks 0..7 | CB: chunks 8..23], c2, code_out = CB@W_out^T,
// loss/ticket zero.
// ---------------------------------------------------------------------------
__global__ __launch_bounds__(256) void prep_kernel(
    const float* __restrict__ codebook, const float* __restrict__ W_in,
    const float* __restrict__ W_out,
    float* __restrict__ loss_acc, unsigned* __restrict__ ticket,
    float* __restrict__ c2, float* __restrict__ code_out,
    unsigned short* __restrict__ BT) {
  const int b = blockIdx.x, t = threadIdx.x;
  if (b < 32) {
    if (b == 0 && t == 0) { *loss_acc = 0.f; *ticket = 0u; }
    int e = b * 8 + (t >> 5);
    int c32 = t & 31, ks = c32 >> 2, kq = c32 & 3;
    const float* src = W_in + e * 256 + c32 * 8;
    float4 x0 = *(const float4*)src, x1 = *(const float4*)(src + 4);
    *(bf16x8*)(BT + ks * 8192 + (e >> 6) * 2048 + ((e >> 4) & 3) * 512 +
               kq * 128 + (e & 15) * 8) = pack8(x0, x1);
  } else if (b < 96) {
    int code = (b - 32) * 8 + (t >> 5);
    int c32 = t & 31, ks = c32 >> 2, kq = c32 & 3;
    const float* src = codebook + code * 256 + c32 * 8;
    float4 x0 = *(const float4*)src, x1 = *(const float4*)(src + 4);
    int cl = code & 255;
    int chunk = 8 + (code >> 8) * 8 + ks;
    *(bf16x8*)(BT + chunk * 8192 + (cl >> 6) * 2048 + ((cl >> 4) & 3) * 512 +
               kq * 128 + (cl & 15) * 8) = pack8(x0, x1);
    float s = x0.x * x0.x + x0.y * x0.y + x0.z * x0.z + x0.w * x0.w +
              x1.x * x1.x + x1.y * x1.y + x1.z * x1.z + x1.w * x1.w;
    s += __shfl_xor(s, 1);  s += __shfl_xor(s, 2);
    s += __shfl_xor(s, 4);  s += __shfl_xor(s, 8);
    s += __shfl_xor(s, 16);
    if ((t & 31) == 0) c2[code] = s;
  } else {
    __shared__ float Cs[32][260];
    __shared__ float Ws[16][260];
    int bi = b - 96, ci = bi & 15, ei = bi >> 4;
    {
      int row = t >> 4, col = (t & 15) * 16;
      const float4* s = (const float4*)(W_out + (size_t)(ei * 16 + row) * 256 + col);
      float4* d = (float4*)&Ws[row][col];
      d[0] = s[0]; d[1] = s[1]; d[2] = s[2]; d[3] = s[3];
    }
    {
      int row = t >> 3, col = (t & 7) * 32;
      const float4* s = (const float4*)(codebook + (size_t)(ci * 32 + row) * 256 + col);
      float4* d = (float4*)&Cs[row][col];
      #pragma unroll
      for (int k = 0; k < 8; k++) d[k] = s[k];
    }
    __syncthreads();
    int c = t & 31, e0 = t >> 5;
    float a0 = 0.f, a1 = 0.f;
    #pragma unroll 4
    for (int d = 0; d < 256; d += 4) {
      float4 cv = *(const float4*)&Cs[c][d];
      float4 w0 = *(const float4*)&Ws[e0][d];
      float4 w1 = *(const float4*)&Ws[e0 + 8][d];
      a0 += cv.x * w0.x + cv.y * w0.y + cv.z * w0.z + cv.w * w0.w;
      a1 += cv.x * w1.x + cv.y * w1.y + cv.z * w1.z + cv.w * w1.w;
    }
    code_out[(size_t)(ci * 32 + c) * 256 + ei * 16 + e0]     = a0;
    code_out[(size_t)(ci * 32 + c) * 256 + ei * 16 + e0 + 8] = a1;
  }
}

// ---------------------------------------------------------------------------
// HZ tile addressing — THE single change vs the verified r6/r0 kernel:
// physical byte = (row*528 + col*2) XOR ((row&7)<<4).
// The XOR flips bits 4..6 only: 16B chunks stay contiguous and aligned, so
// every bf16x8 access is a legal ds_*_b128; it permutes 16B slots within each
// 128B window so the A-frag reads (row varies with l15, col fixed per quad)
// drop from 8-way to 2-way bank conflict (T2 / G4).  Values and op order are
// bit-identical to r0 — pure layout.  ALL HZ accesses go through this helper.
// ---------------------------------------------------------------------------
__device__ __forceinline__ unsigned short* hz_at(unsigned short* base, int row, int col) {
  int b = row * 528 + col * 2;
  b ^= (row & 7) << 4;
  return (unsigned short*)((char*)base + b);
}

__global__ __launch_bounds__(512, 4) void main_kernel(
    const float* __restrict__ hidden, const int* __restrict__ mask,
    const float* __restrict__ gamma, const float* __restrict__ beta,
    const float* __restrict__ c2g, const float* __restrict__ code_out,
    const unsigned short* __restrict__ BT,
    float* __restrict__ loss_acc, unsigned* __restrict__ ticket,
    float* __restrict__ out) {

  __shared__ unsigned short HZ[64 * 264];   // H then Z (33792 B), stride 264
  __shared__ float    z2[64];
  __shared__ unsigned sminp[512];
  __shared__ int      ridx[64];

  const int t    = threadIdx.x;             // 0..511
  const int lane = t & 63;
  const int w    = t >> 6;                  // wave 0..7
  const int l15  = lane & 15;
  const int quad = lane >> 4;
  const int row0 = blockIdx.x * 64;

  // c2 for this wave's 2x32 code columns
  float ccp[2][2];
  #pragma unroll
  for (int p = 0; p < 2; p++)
    #pragma unroll
    for (int j = 0; j < 2; j++)
      ccp[p][j] = c2g[p * 256 + w * 32 + j * 16 + l15];

  // ---- stage H: contiguous global reads, b128 LDS writes (swizzled) ----
  {
    #pragma unroll
    for (int i = 0; i < 4; i++) {
      int flat = (t * 8) + i * 4096;        // float index in 64x256 tile
      int r = flat >> 8, c = flat & 255;
      const float* src = hidden + (size_t)row0 * 256 + flat;
      float4 x0 = *(const float4*)src, x1 = *(const float4*)(src + 4);
      *(bf16x8*)hz_at(HZ, r, c) = pack8(x0, x1);
    }
  }
  __syncthreads();   // H visible

  const f32x4 zf = {0.f, 0.f, 0.f, 0.f};
  f32x4 acc[4][2];
  #pragma unroll
  for (int i = 0; i < 4; i++)
    #pragma unroll
    for (int j = 0; j < 2; j++) acc[i][j] = zf;

  // b-frag address: BT + chunk*8192 + w*1024 + j*512 + quad*128 + l15*8
  const unsigned short* BTw = BT + w * 1024 + lane * 8;

  // ---------------- Phase 1: Z = H * W_in^T ----------------
  #pragma unroll 2
  for (int ks = 0; ks < 8; ks++) {
    const unsigned short* bp = BTw + ks * 8192;
    bf16x8 b0 = *(const bf16x8*)(bp);
    bf16x8 b1 = *(const bf16x8*)(bp + 512);
    bf16x8 a[4];
    #pragma unroll
    for (int i = 0; i < 4; i++)
      a[i] = *(const bf16x8*)hz_at(HZ, i * 16 + l15, ks * 32 + quad * 8);
    #pragma unroll
    for (int i = 0; i < 4; i++) {
      acc[i][0] = __builtin_amdgcn_mfma_f32_16x16x32_bf16(a[i], b0, acc[i][0], 0, 0, 0);
      acc[i][1] = __builtin_amdgcn_mfma_f32_16x16x32_bf16(a[i], b1, acc[i][1], 0, 0, 0);
    }
  }

  __syncthreads();   // all H reads done
  // Z epilogue: C/D layout row = quad*4+reg, col = lane&15 (swizzled store)
  #pragma unroll
  for (int i = 0; i < 4; i++)
    #pragma unroll
    for (int j = 0; j < 2; j++)
      #pragma unroll
      for (int r = 0; r < 4; r++)
        *hz_at(HZ, i * 16 + quad * 4 + r, w * 32 + j * 16 + l15) =
            f2bf(acc[i][j][r]);
  __syncthreads();   // Z visible

  { // |z|^2 per row from bf16 Z (consistent with scores)
    int zr = t >> 3, part = t & 7;
    float s = 0.f;
    #pragma unroll
    for (int c = 0; c < 32; c += 8) {
      bf16x8 v = *(const bf16x8*)hz_at(HZ, zr, part * 32 + c);
      #pragma unroll
      for (int e = 0; e < 8; e++) { float f = bf2f((unsigned short)v[e]); s += f * f; }
    }
    s += __shfl_xor(s, 1);
    s += __shfl_xor(s, 2);
    s += __shfl_xor(s, 4);
    if (part == 0) z2[zr] = s;
  }

  // ---------------- Phase 2: scores + packed argmin ----------------
  unsigned runp[16];
  #pragma unroll
  for (int r = 0; r < 16; r++) runp[r] = 0xFFFFFFFFu;

  #pragma unroll
  for (int pass = 0; pass < 2; pass++) {
    #pragma unroll
    for (int i = 0; i < 4; i++)
      #pragma unroll
      for (int j = 0; j < 2; j++) acc[i][j] = zf;

    #pragma unroll 2
    for (int ks = 0; ks < 8; ks++) {
      const unsigned short* bp = BTw + (8 + pass * 8 + ks) * 8192;
      bf16x8 b0 = *(const bf16x8*)(bp);
      bf16x8 b1 = *(const bf16x8*)(bp + 512);
      bf16x8 a[4];
      #pragma unroll
      for (int i = 0; i < 4; i++)
        a[i] = *(const bf16x8*)hz_at(HZ, i * 16 + l15, ks * 32 + quad * 8);
      #pragma unroll
      for (int i = 0; i < 4; i++) {
        acc[i][0] = __builtin_amdgcn_mfma_f32_16x16x32_bf16(a[i], b0, acc[i][0], 0, 0, 0);
        acc[i][1] = __builtin_amdgcn_mfma_f32_16x16x32_bf16(a[i], b1, acc[i][1], 0, 0, 0);
      }
    }
    // fold: m = c2 - 2 z.c ; pack sortable (dist | 9-bit code); min
    #pragma unroll
    for (int i = 0; i < 4; i++)
      #pragma unroll
      for (int j = 0; j < 2; j++) {
        int code = pass * 256 + w * 32 + j * 16 + l15;
        float cc = ccp[pass][j];
        #pragma unroll
        for (int r = 0; r < 4; r++) {
          float m = cc - 2.f * acc[i][j][r];
          unsigned bits = __float_as_uint(m);
          unsigned u = bits ^ (0x80000000u | (unsigned)((int)bits >> 31));
          unsigned p = (u & 0xFFFFFE00u) | (unsigned)code;
          int ri = i * 4 + r;
          runp[ri] = min(runp[ri], p);
        }
      }
  }

  // reduce across the 16 lanes of each quad group
  #pragma unroll
  for (int ri = 0; ri < 16; ri++) {
    unsigned v = runp[ri];
    v = min(v, (unsigned)__shfl_xor((int)v, 1));
    v = min(v, (unsigned)__shfl_xor((int)v, 2));
    v = min(v, (unsigned)__shfl_xor((int)v, 4));
    v = min(v, (unsigned)__shfl_xor((int)v, 8));
    if (l15 == 0) {
      int i = ri >> 2, r = ri & 3;
      sminp[w * 64 + (i * 16 + quad * 4 + r)] = v;
    }
  }
  __syncthreads();

  if (t < 64) { // merge 8 waves, finalize idx + dist, block loss + ticket
    int row = t;
    unsigned bv = sminp[row];
    #pragma unroll
    for (int ww = 1; ww < 8; ww++) bv = min(bv, sminp[ww * 64 + row]);
    ridx[row] = (int)(bv & 511u);
    unsigned u = bv & 0xFFFFFE00u;
    unsigned bits = (u & 0x80000000u) ? (u ^ 0x80000000u) : ~u;
    float dist = z2[row] + __uint_as_float(bits);
    #pragma unroll
    for (int m = 1; m < 64; m <<= 1) dist += __shfl_xor(dist, m);
    if (t == 0) {
      atomicAdd(loss_acc, dist);
      __threadfence();
      unsigned done = atomicAdd(ticket, 1u);
      if (done == gridDim.x - 1) {
        float total = atomicAdd(loss_acc, 0.f);
        out[16777216] = 1.25f * total * (1.f / 16777216.f);
      }
    }
  }
  __syncthreads();

  // ---- phase 3 (r0-exact: full-wave coalesced LN) ----
  {
    float4 g4 = *(const float4*)(gamma + lane * 4);
    float4 b4 = *(const float4*)(beta + lane * 4);
    for (int rr = 0; rr < 8; rr++) {
      int row = w * 8 + rr;
      int gr  = row0 + row;
      float4 h = *(const float4*)(hidden + (size_t)gr * 256 + lane * 4);
      int code = ridx[row];
      float4 o = *(const float4*)(code_out + (size_t)code * 256 + lane * 4);
      float mf = mask[gr] ? 1.f : 0.f;
      h.x += mf * o.x; h.y += mf * o.y; h.z += mf * o.z; h.w += mf * o.w;
      float s  = h.x + h.y + h.z + h.w;
      float sq = h.x * h.x + h.y * h.y + h.z * h.z + h.w * h.w;
      #pragma unroll
      for (int m = 1; m < 64; m <<= 1) { s += __shfl_xor(s, m); sq += __shfl_xor(sq, m); }
      float mean = s * (1.f / 256.f);
      float var  = sq * (1.f / 256.f) - mean * mean;
      float rstd = rsqrtf(var + LN_EPS);
      float4 res;
      res.x = (h.x - mean) * rstd * g4.x + b4.x;
      res.y = (h.y - mean) * rstd * g4.y + b4.y;
      res.z = (h.z - mean) * rstd * g4.z + b4.z;
      res.w = (h.w - mean) * rstd * g4.w + b4.w;
      *(float4*)(out + (size_t)gr * 256 + lane * 4) = res;
    }
  }
}

extern "C" void kernel_launch(void* const* d_in, const int* in_sizes, int n_in,
                              void* d_out, int out_size, void* d_ws, size_t ws_size,
                              hipStream_t stream) {
  (void)in_sizes; (void)n_in; (void)out_size; (void)ws_size;
  const float* hidden   = (const float*)d_in[0];
  const int*   mask     = (const int*)d_in[1];
  const float* codebook = (const float*)d_in[2];
  const float* W_in     = (const float*)d_in[3];
  const float* W_out    = (const float*)d_in[4];
  const float* gamma    = (const float*)d_in[5];
  const float* beta     = (const float*)d_in[6];
  float* out = (float*)d_out;

  float* wsf      = (float*)d_ws;
  float* loss_acc = wsf;                        // [1]
  unsigned* ticket = (unsigned*)(wsf + 1);      // [1]
  float* c2       = wsf + 64;                   // [512]
  float* code_out = wsf + 64 + 512;             // [512*256]
  unsigned short* BT = (unsigned short*)(wsf + 64 + 512 + 512 * 256); // 24*8192 bf16

  prep_kernel<<<352, 256, 0, stream>>>(codebook, W_in, W_out, loss_acc, ticket,
                                       c2, code_out, BT);
  main_kernel<<<1024, 512, 0, stream>>>(hidden, mask, gamma, beta, c2, code_out,
                                        BT, loss_acc, ticket, out);
}

// Round 9
// 185.523 us; speedup vs baseline: 1.3588x; 1.0568x over previous
//
#include <hip/hip_runtime.h>

#define LN_EPS 1e-5f

typedef short bf16x8 __attribute__((ext_vector_type(8)));
typedef float f32x4  __attribute__((ext_vector_type(4)));

__device__ __forceinline__ unsigned short f2bf(float f) {
  unsigned u = __float_as_uint(f);
  u += 0x7fffu + ((u >> 16) & 1u);          // RNE
  return (unsigned short)(u >> 16);
}
__device__ __forceinline__ float bf2f(unsigned short s) {
  return __uint_as_float(((unsigned)s) << 16);
}

__device__ __forceinline__ bf16x8 pack8(float4 a, float4 b) {
  bf16x8 v;
  v[0] = (short)f2bf(a.x); v[1] = (short)f2bf(a.y);
  v[2] = (short)f2bf(a.z); v[3] = (short)f2bf(a.w);
  v[4] = (short)f2bf(b.x); v[5] = (short)f2bf(b.y);
  v[6] = (short)f2bf(b.z); v[7] = (short)f2bf(b.w);
  return v;
}

// ---------------------------------------------------------------------------
// Prep (byte-identical to the verified r0 kernel): BT = pre-tiled bf16 image
// of [W_in: chunks 0..7 | CB: chunks 8..23], c2, code_out = CB@W_out^T,
// loss/ticket zero.
// ---------------------------------------------------------------------------
__global__ __launch_bounds__(256) void prep_kernel(
    const float* __restrict__ codebook, const float* __restrict__ W_in,
    const float* __restrict__ W_out,
    float* __restrict__ loss_acc, unsigned* __restrict__ ticket,
    float* __restrict__ c2, float* __restrict__ code_out,
    unsigned short* __restrict__ BT) {
  const int b = blockIdx.x, t = threadIdx.x;
  if (b < 32) {
    if (b == 0 && t == 0) { *loss_acc = 0.f; *ticket = 0u; }
    int e = b * 8 + (t >> 5);
    int c32 = t & 31, ks = c32 >> 2, kq = c32 & 3;
    const float* src = W_in + e * 256 + c32 * 8;
    float4 x0 = *(const float4*)src, x1 = *(const float4*)(src + 4);
    *(bf16x8*)(BT + ks * 8192 + (e >> 6) * 2048 + ((e >> 4) & 3) * 512 +
               kq * 128 + (e & 15) * 8) = pack8(x0, x1);
  } else if (b < 96) {
    int code = (b - 32) * 8 + (t >> 5);
    int c32 = t & 31, ks = c32 >> 2, kq = c32 & 3;
    const float* src = codebook + code * 256 + c32 * 8;
    float4 x0 = *(const float4*)src, x1 = *(const float4*)(src + 4);
    int cl = code & 255;
    int chunk = 8 + (code >> 8) * 8 + ks;
    *(bf16x8*)(BT + chunk * 8192 + (cl >> 6) * 2048 + ((cl >> 4) & 3) * 512 +
               kq * 128 + (cl & 15) * 8) = pack8(x0, x1);
    float s = x0.x * x0.x + x0.y * x0.y + x0.z * x0.z + x0.w * x0.w +
              x1.x * x1.x + x1.y * x1.y + x1.z * x1.z + x1.w * x1.w;
    s += __shfl_xor(s, 1);  s += __shfl_xor(s, 2);
    s += __shfl_xor(s, 4);  s += __shfl_xor(s, 8);
    s += __shfl_xor(s, 16);
    if ((t & 31) == 0) c2[code] = s;
  } else {
    __shared__ float Cs[32][260];
    __shared__ float Ws[16][260];
    int bi = b - 96, ci = bi & 15, ei = bi >> 4;
    {
      int row = t >> 4, col = (t & 15) * 16;
      const float4* s = (const float4*)(W_out + (size_t)(ei * 16 + row) * 256 + col);
      float4* d = (float4*)&Ws[row][col];
      d[0] = s[0]; d[1] = s[1]; d[2] = s[2]; d[3] = s[3];
    }
    {
      int row = t >> 3, col = (t & 7) * 32;
      const float4* s = (const float4*)(codebook + (size_t)(ci * 32 + row) * 256 + col);
      float4* d = (float4*)&Cs[row][col];
      #pragma unroll
      for (int k = 0; k < 8; k++) d[k] = s[k];
    }
    __syncthreads();
    int c = t & 31, e0 = t >> 5;
    float a0 = 0.f, a1 = 0.f;
    #pragma unroll 4
    for (int d = 0; d < 256; d += 4) {
      float4 cv = *(const float4*)&Cs[c][d];
      float4 w0 = *(const float4*)&Ws[e0][d];
      float4 w1 = *(const float4*)&Ws[e0 + 8][d];
      a0 += cv.x * w0.x + cv.y * w0.y + cv.z * w0.z + cv.w * w0.w;
      a1 += cv.x * w1.x + cv.y * w1.y + cv.z * w1.z + cv.w * w1.w;
    }
    code_out[(size_t)(ci * 32 + c) * 256 + ei * 16 + e0]     = a0;
    code_out[(size_t)(ci * 32 + c) * 256 + ei * 16 + e0 + 8] = a1;
  }
}

// ---------------------------------------------------------------------------
// Main: r0 structure and layout (stride 264, NO xor swizzle — r8 showed the
// odd stride is already a built-in bank rotation; adding XOR cancelled it).
// Single change vs r0: phase-1 MFMA operands swapped -> lane holds 4
// CONSECUTIVE e-cols of one Z-row, so (a) Z write-back is 8x ds_write_b64
// instead of 32x ds_write_b16, and (b) z2 is computed from registers
// (+2 shuffles per i, partials in z2p[8][64]) — the z2 LDS-read pass is gone.
// Phase 2 reads identical Z values from identical addresses -> idx bit-equal
// to r0; only the loss z2 summation order changes (f32 ~1e-6).
// ---------------------------------------------------------------------------
__global__ __launch_bounds__(512, 4) void main_kernel(
    const float* __restrict__ hidden, const int* __restrict__ mask,
    const float* __restrict__ gamma, const float* __restrict__ beta,
    const float* __restrict__ c2g, const float* __restrict__ code_out,
    const unsigned short* __restrict__ BT,
    float* __restrict__ loss_acc, unsigned* __restrict__ ticket,
    float* __restrict__ out) {

  __shared__ unsigned short HZ[64 * 264];   // H then Z (33792 B), stride 264
  __shared__ float    z2p[8][64];           // per-wave z2 partials (2 KB)
  __shared__ unsigned sminp[512];
  __shared__ int      ridx[64];

  const int t    = threadIdx.x;             // 0..511
  const int lane = t & 63;
  const int w    = t >> 6;                  // wave 0..7
  const int l15  = lane & 15;
  const int quad = lane >> 4;
  const int row0 = blockIdx.x * 64;

  // c2 for this wave's 2x32 code columns
  float ccp[2][2];
  #pragma unroll
  for (int p = 0; p < 2; p++)
    #pragma unroll
    for (int j = 0; j < 2; j++)
      ccp[p][j] = c2g[p * 256 + w * 32 + j * 16 + l15];

  // ---- stage H: contiguous global reads, b128 LDS writes ----
  {
    #pragma unroll
    for (int i = 0; i < 4; i++) {
      int flat = (t * 8) + i * 4096;        // float index in 64x256 tile
      int r = flat >> 8, c = flat & 255;
      const float* src = hidden + (size_t)row0 * 256 + flat;
      float4 x0 = *(const float4*)src, x1 = *(const float4*)(src + 4);
      *(bf16x8*)(HZ + r * 264 + c) = pack8(x0, x1);
    }
  }
  __syncthreads();   // H visible

  const f32x4 zf = {0.f, 0.f, 0.f, 0.f};
  f32x4 acc[4][2];
  #pragma unroll
  for (int i = 0; i < 4; i++)
    #pragma unroll
    for (int j = 0; j < 2; j++) acc[i][j] = zf;

  // b-frag address: BT + chunk*8192 + w*1024 + j*512 + quad*128 + l15*8
  const unsigned short* BTw = BT + w * 1024 + lane * 8;

  // ---------------- Phase 1: Z = H * W_in^T (operands SWAPPED) ----------
  // acc[i][j][r] = Z[i*16 + l15][w*32 + j*16 + quad*4 + r]
  #pragma unroll 2
  for (int ks = 0; ks < 8; ks++) {
    const unsigned short* bp = BTw + ks * 8192;
    bf16x8 b0 = *(const bf16x8*)(bp);
    bf16x8 b1 = *(const bf16x8*)(bp + 512);
    bf16x8 a[4];
    #pragma unroll
    for (int i = 0; i < 4; i++)
      a[i] = *(const bf16x8*)(HZ + (i * 16 + l15) * 264 + ks * 32 + quad * 8);
    #pragma unroll
    for (int i = 0; i < 4; i++) {
      acc[i][0] = __builtin_amdgcn_mfma_f32_16x16x32_bf16(b0, a[i], acc[i][0], 0, 0, 0);
      acc[i][1] = __builtin_amdgcn_mfma_f32_16x16x32_bf16(b1, a[i], acc[i][1], 0, 0, 0);
    }
  }

  // ---- z2 from registers (bf16-consistent), before any barrier ----
  // per lane: 8 cols of row i*16+l15; reduce across quads (same l15).
  {
    #pragma unroll
    for (int i = 0; i < 4; i++) {
      float zs = 0.f;
      #pragma unroll
      for (int j = 0; j < 2; j++)
        #pragma unroll
        for (int r = 0; r < 4; r++) {
          float f = bf2f(f2bf(acc[i][j][r]));
          zs += f * f;
        }
      zs += __shfl_xor(zs, 16);
      zs += __shfl_xor(zs, 32);
      if (quad == 0) z2p[w][i * 16 + l15] = zs;
    }
  }
  __syncthreads();   // all H reads done (and z2p written)

  // Z epilogue: lane writes 4 consecutive cols of row i*16+l15 -> b64
  #pragma unroll
  for (int i = 0; i < 4; i++)
    #pragma unroll
    for (int j = 0; j < 2; j++) {
      unsigned short z4[4];
      #pragma unroll
      for (int r = 0; r < 4; r++) z4[r] = f2bf(acc[i][j][r]);
      unsigned lo = (unsigned)z4[0] | ((unsigned)z4[1] << 16);
      unsigned hi = (unsigned)z4[2] | ((unsigned)z4[3] << 16);
      uint2 pv; pv.x = lo; pv.y = hi;
      *(uint2*)(HZ + (i * 16 + l15) * 264 + (w * 32 + j * 16 + quad * 4)) = pv;
    }
  __syncthreads();   // Z visible

  // ---------------- Phase 2: scores + packed argmin ----------------
  unsigned runp[16];
  #pragma unroll
  for (int r = 0; r < 16; r++) runp[r] = 0xFFFFFFFFu;

  #pragma unroll
  for (int pass = 0; pass < 2; pass++) {
    #pragma unroll
    for (int i = 0; i < 4; i++)
      #pragma unroll
      for (int j = 0; j < 2; j++) acc[i][j] = zf;

    #pragma unroll 2
    for (int ks = 0; ks < 8; ks++) {
      const unsigned short* bp = BTw + (8 + pass * 8 + ks) * 8192;
      bf16x8 b0 = *(const bf16x8*)(bp);
      bf16x8 b1 = *(const bf16x8*)(bp + 512);
      bf16x8 a[4];
      #pragma unroll
      for (int i = 0; i < 4; i++)
        a[i] = *(const bf16x8*)(HZ + (i * 16 + l15) * 264 + ks * 32 + quad * 8);
      #pragma unroll
      for (int i = 0; i < 4; i++) {
        acc[i][0] = __builtin_amdgcn_mfma_f32_16x16x32_bf16(a[i], b0, acc[i][0], 0, 0, 0);
        acc[i][1] = __builtin_amdgcn_mfma_f32_16x16x32_bf16(a[i], b1, acc[i][1], 0, 0, 0);
      }
    }
    // fold: m = c2 - 2 z.c ; pack sortable (dist | 9-bit code); min
    #pragma unroll
    for (int i = 0; i < 4; i++)
      #pragma unroll
      for (int j = 0; j < 2; j++) {
        int code = pass * 256 + w * 32 + j * 16 + l15;
        float cc = ccp[pass][j];
        #pragma unroll
        for (int r = 0; r < 4; r++) {
          float m = cc - 2.f * acc[i][j][r];
          unsigned bits = __float_as_uint(m);
          unsigned u = bits ^ (0x80000000u | (unsigned)((int)bits >> 31));
          unsigned p = (u & 0xFFFFFE00u) | (unsigned)code;
          int ri = i * 4 + r;
          runp[ri] = min(runp[ri], p);
        }
      }
  }

  // reduce across the 16 lanes of each quad group
  #pragma unroll
  for (int ri = 0; ri < 16; ri++) {
    unsigned v = runp[ri];
    v = min(v, (unsigned)__shfl_xor((int)v, 1));
    v = min(v, (unsigned)__shfl_xor((int)v, 2));
    v = min(v, (unsigned)__shfl_xor((int)v, 4));
    v = min(v, (unsigned)__shfl_xor((int)v, 8));
    if (l15 == 0) {
      int i = ri >> 2, r = ri & 3;
      sminp[w * 64 + (i * 16 + quad * 4 + r)] = v;
    }
  }
  __syncthreads();

  if (t < 64) { // merge 8 waves, finalize idx + dist, block loss + ticket
    int row = t;
    unsigned bv = sminp[row];
    #pragma unroll
    for (int ww = 1; ww < 8; ww++) bv = min(bv, sminp[ww * 64 + row]);
    ridx[row] = (int)(bv & 511u);
    float z2row = z2p[0][row];
    #pragma unroll
    for (int ww = 1; ww < 8; ww++) z2row += z2p[ww][row];
    unsigned u = bv & 0xFFFFFE00u;
    unsigned bits = (u & 0x80000000u) ? (u ^ 0x80000000u) : ~u;
    float dist = z2row + __uint_as_float(bits);
    #pragma unroll
    for (int m = 1; m < 64; m <<= 1) dist += __shfl_xor(dist, m);
    if (t == 0) {
      atomicAdd(loss_acc, dist);
      __threadfence();
      unsigned done = atomicAdd(ticket, 1u);
      if (done == gridDim.x - 1) {
        float total = atomicAdd(loss_acc, 0.f);
        out[16777216] = 1.25f * total * (1.f / 16777216.f);
      }
    }
  }
  __syncthreads();

  // ---- phase 3 (r0-exact: full-wave coalesced LN) ----
  {
    float4 g4 = *(const float4*)(gamma + lane * 4);
    float4 b4 = *(const float4*)(beta + lane * 4);
    for (int rr = 0; rr < 8; rr++) {
      int row = w * 8 + rr;
      int gr  = row0 + row;
      float4 h = *(const float4*)(hidden + (size_t)gr * 256 + lane * 4);
      int code = ridx[row];
      float4 o = *(const float4*)(code_out + (size_t)code * 256 + lane * 4);
      float mf = mask[gr] ? 1.f : 0.f;
      h.x += mf * o.x; h.y += mf * o.y; h.z += mf * o.z; h.w += mf * o.w;
      float s  = h.x + h.y + h.z + h.w;
      float sq = h.x * h.x + h.y * h.y + h.z * h.z + h.w * h.w;
      #pragma unroll
      for (int m = 1; m < 64; m <<= 1) { s += __shfl_xor(s, m); sq += __shfl_xor(sq, m); }
      float mean = s * (1.f / 256.f);
      float var  = sq * (1.f / 256.f) - mean * mean;
      float rstd = rsqrtf(var + LN_EPS);
      float4 res;
      res.x = (h.x - mean) * rstd * g4.x + b4.x;
      res.y = (h.y - mean) * rstd * g4.y + b4.y;
      res.z = (h.z - mean) * rstd * g4.z + b4.z;
      res.w = (h.w - mean) * rstd * g4.w + b4.w;
      *(float4*)(out + (size_t)gr * 256 + lane * 4) = res;
    }
  }
}

extern "C" void kernel_launch(void* const* d_in, const int* in_sizes, int n_in,
                              void* d_out, int out_size, void* d_ws, size_t ws_size,
                              hipStream_t stream) {
  (void)in_sizes; (void)n_in; (void)out_size; (void)ws_size;
  const float* hidden   = (const float*)d_in[0];
  const int*   mask     = (const int*)d_in[1];
  const float* codebook = (const float*)d_in[2];
  const float* W_in     = (const float*)d_in[3];
  const float* W_out    = (const float*)d_in[4];
  const float* gamma    = (const float*)d_in[5];
  const float* beta     = (const float*)d_in[6];
  float* out = (float*)d_out;

  float* wsf      = (float*)d_ws;
  float* loss_acc = wsf;                        // [1]
  unsigned* ticket = (unsigned*)(wsf + 1);      // [1]
  float* c2       = wsf + 64;                   // [512]
  float* code_out = wsf + 64 + 512;             // [512*256]
  unsigned short* BT = (unsigned short*)(wsf + 64 + 512 + 512 * 256); // 24*8192 bf16

  prep_kernel<<<352, 256, 0, stream>>>(codebook, W_in, W_out, loss_acc, ticket,
                                       c2, code_out, BT);
  main_kernel<<<1024, 512, 0, stream>>>(hidden, mask, gamma, beta, c2, code_out,
                                        BT, loss_acc, ticket, out);
}